// Round 9
// baseline (245.944 us; speedup 1.0000x reference)
//
#include <hip/hip_runtime.h>

#define N_DIM 8192   // rows of features / columns of w / output length
#define K_DIM 512    // inner dim of features @ E
#define D_DIM 4096   // columns of E / rows of w

typedef __bf16 bf16x8 __attribute__((ext_vector_type(8)));
typedef float  f32x16 __attribute__((ext_vector_type(16)));
typedef unsigned short u16x8 __attribute__((ext_vector_type(8)));

__device__ __forceinline__ unsigned short f2bf(float f) {
    union { float f; unsigned int u; } v; v.f = f;
    unsigned int r = v.u + 0x7FFF + ((v.u >> 16) & 1);   // RNE
    return (unsigned short)(r >> 16);
}

// ---------------------------------------------------------------------------
// Kernel 1: E [512][4096] f32 -> ETf bf16 in FRAGMENT-MAJOR layout:
// frag(d,k) = (d>>5)*32 + (k>>4); within frag, lane = ((k>>3)&1)*32 + (d&31)
// holds 8 k-contiguous bf16 at shorts[frag*512 + lane*8]. One 32x32x16 MFMA
// A-fragment = 1 KB contiguous -> af load is a fully-coalesced dwordx4.
// ---------------------------------------------------------------------------
__global__ __launch_bounds__(256) void transpose_E(const float* __restrict__ E,
                                                   unsigned short* __restrict__ ETf) {
    __shared__ float tile[64][65];    // [k_local][d_local]
    const int d0 = blockIdx.x * 64;
    const int k0 = blockIdx.y * 64;
    const int tid = threadIdx.x;
    {
        const int r  = tid / 16;          // 0..15
        const int c4 = (tid % 16) * 4;    // 0..60
#pragma unroll
        for (int p = 0; p < 4; ++p) {
            int k = p * 16 + r;
            float4 v = *reinterpret_cast<const float4*>(E + (size_t)(k0 + k) * D_DIM + d0 + c4);
            tile[k][c4 + 0] = v.x; tile[k][c4 + 1] = v.y;
            tile[k][c4 + 2] = v.z; tile[k][c4 + 3] = v.w;
        }
    }
    __syncthreads();
    const int lane = tid & 63;
    const int w    = tid >> 6;        // k16-frag within tile (0..3)
    const int dl5  = lane & 31;
    const int k8h  = lane >> 5;
#pragma unroll
    for (int q = 0; q < 2; ++q) {     // d-half of tile
        u16x8 o;
#pragma unroll
        for (int j = 0; j < 8; ++j)
            o[j] = f2bf(tile[w * 16 + k8h * 8 + j][q * 32 + dl5]);
        const int frag = ((d0 >> 5) + q) * 32 + (k0 >> 4) + w;
        *reinterpret_cast<u16x8*>(ETf + (size_t)frag * 512 + lane * 8) = o;
    }
}

// ---------------------------------------------------------------------------
// Kernel 2: F [8192][512] f32 -> FBf bf16 in the SAME fragment-major layout
// (frag = (n>>5)*32 + (k>>4); lane = ((k>>3)&1)*32 + (n&31)).
// Block = 32 n-rows x 512 k; LDS round-trip keeps both global sides coalesced.
// ---------------------------------------------------------------------------
__global__ __launch_bounds__(256) void convert_F(const float* __restrict__ F,
                                                 unsigned short* __restrict__ FBf) {
    __shared__ unsigned short tl[32 * 520];   // padded rows (520) -> phase-2 reads conflict-free
    const int t  = threadIdx.x;
    const int n5 = blockIdx.x;                // 0..255
    const float* Fb = F + (size_t)n5 * 32 * K_DIM;
#pragma unroll
    for (int it = 0; it < 8; ++it) {
        const int c  = it * 256 + t;          // 8-float chunk id
        const int n  = c >> 6;                // 0..31
        const int kc = (c & 63) * 8;
        float4 a = *reinterpret_cast<const float4*>(Fb + n * K_DIM + kc);
        float4 b = *reinterpret_cast<const float4*>(Fb + n * K_DIM + kc + 4);
        u16x8 o;
        o[0] = f2bf(a.x); o[1] = f2bf(a.y); o[2] = f2bf(a.z); o[3] = f2bf(a.w);
        o[4] = f2bf(b.x); o[5] = f2bf(b.y); o[6] = f2bf(b.z); o[7] = f2bf(b.w);
        *reinterpret_cast<u16x8*>(tl + n * 520 + kc) = o;
    }
    __syncthreads();
    unsigned short* outb = FBf + (size_t)n5 * 32 * K_DIM;   // 16384 shorts
#pragma unroll
    for (int it = 0; it < 8; ++it) {
        const int o    = it * 256 + t;
        const int k4   = o >> 6;              // frag (k16) index 0..31
        const int lane = o & 63;
        const int n    = lane & 31;
        const int kh   = (lane >> 5) * 8;
        u16x8 v = *reinterpret_cast<const u16x8*>(tl + n * 520 + k4 * 16 + kh);
        *reinterpret_cast<u16x8*>(outb + k4 * 512 + lane * 8) = v;
    }
}

// ---------------------------------------------------------------------------
// Kernel 3: fused  out[n] = sum_d (F@E + b)[n,d] * w[d,n], computed as y^T.
// R9: NO-LDS, NO-BARRIER main loop — both operands read directly from global
// in fragment-major layout (coalesced dwordx4 per fragment, L2-resident via
// XCD-rectangle swizzle). The freed LDS holds the block's 128x128 f32 W-tile,
// prefetched via global_load_lds (NT) spread across the K-loop so the W HBM
// stream overlaps compute. One barrier before the epilogue; W then read from
// LDS (bank = lane, conflict-free). Bias + shfl + atomics as before.
// ---------------------------------------------------------------------------
__global__ __launch_bounds__(256) void gemm_fused(const unsigned short* __restrict__ FBf,
                                                  const float* __restrict__ W,
                                                  const unsigned short* __restrict__ ETf,
                                                  const float* __restrict__ B,
                                                  float* __restrict__ out) {
    __shared__ float Wsh[128 * 128];   // 64 KB W-tile [d_local][n_local]

    const int tid  = threadIdx.x;
    const int wave = tid >> 6;
    const int lane = tid & 63;
    const int wy   = wave >> 1;     // d-direction wave coord (0..1)
    const int wx   = wave & 1;      // n-direction wave coord (0..1)
    const int l31  = lane & 31;
    const int half = lane >> 5;

    // --- XCD-rectangle swizzle (bijection on 64x32 tile grid) ---
    const int f   = blockIdx.x + ((int)gridDim.x) * blockIdx.y;
    const int xcd = f & 7;
    const int s   = f >> 3;                        // 0..255 within XCD
    const int ntile = (xcd & 3) * 16 + (s & 15);   // 0..63
    const int dtile = (xcd >> 2) * 16 + (s >> 4);  // 0..31
    const int n0 = ntile * 128;
    const int d0 = dtile * 128;

    f32x16 acc[2][2] = {};   // [mi=d-tile][ni=n-tile]

    // fragment-major base pointers (lane chunk folded in); mi/ni stride 16384 shorts
    const unsigned short* pa = ETf + (size_t)((d0 >> 5) + wy * 2) * 16384 + lane * 8;
    const unsigned short* pb = FBf + (size_t)((n0 >> 5) + wx * 2) * 16384 + lane * 8;

    // W staging: per-lane source (row pair 2i,2i+1; 4 floats per lane),
    // LDS dest wave-uniform + lane*16
    const int wrow = lane >> 5;             // 0/1
    const int wcol = (lane & 31) * 4;

    for (int kt = 0; kt < 8; ++kt) {
        // --- W-tile prefetch slice: 2 KB per wave per kt ---
#pragma unroll
        for (int jj = 0; jj < 2; ++jj) {
            const int i = kt * 8 + wave * 2 + jj;     // 0..63 -> rows 2i, 2i+1
            const float* gw = W + (size_t)(d0 + 2 * i + wrow) * N_DIM + n0 + wcol;
            __builtin_amdgcn_global_load_lds(
                (const __attribute__((address_space(1))) void*)gw,
                (__attribute__((address_space(3))) void*)(Wsh + i * 256),
                16, 0, 2 /* NT */);
        }
        // --- 4 k16-steps: direct fragment loads + MFMA ---
#pragma unroll
        for (int ks = 0; ks < 4; ++ks) {
            const int k16 = kt * 4 + ks;
            bf16x8 af0 = *reinterpret_cast<const bf16x8*>(pa + (size_t)k16 * 512);
            bf16x8 af1 = *reinterpret_cast<const bf16x8*>(pa + 16384 + (size_t)k16 * 512);
            bf16x8 bf0 = *reinterpret_cast<const bf16x8*>(pb + (size_t)k16 * 512);
            bf16x8 bf1 = *reinterpret_cast<const bf16x8*>(pb + 16384 + (size_t)k16 * 512);
            acc[0][0] = __builtin_amdgcn_mfma_f32_32x32x16_bf16(af0, bf0, acc[0][0], 0, 0, 0);
            acc[0][1] = __builtin_amdgcn_mfma_f32_32x32x16_bf16(af0, bf1, acc[0][1], 0, 0, 0);
            acc[1][0] = __builtin_amdgcn_mfma_f32_32x32x16_bf16(af1, bf0, acc[1][0], 0, 0, 0);
            acc[1][1] = __builtin_amdgcn_mfma_f32_32x32x16_bf16(af1, bf1, acc[1][1], 0, 0, 0);
        }
    }

    __syncthreads();   // drains vmcnt -> Wsh complete

    // --- epilogue: C layout 32x32: col(n)=lane&31, row(d)=(reg&3)+8*(reg>>2)+4*half
    const int nbl = wx * 64;                 // local n base
    float part0 = 0.f, part1 = 0.f;
#pragma unroll
    for (int mi = 0; mi < 2; ++mi) {
        const int dlb = wy * 64 + mi * 32 + 4 * half;
#pragma unroll
        for (int reg = 0; reg < 16; ++reg) {
            const int dl = dlb + (reg & 3) + 8 * (reg >> 2);
            const float bd = B[d0 + dl];
            const float* wr = Wsh + dl * 128 + nbl;
            part0 += (acc[mi][0][reg] + bd) * wr[l31];
            part1 += (acc[mi][1][reg] + bd) * wr[32 + l31];
        }
    }
    part0 += __shfl_xor(part0, 32);
    part1 += __shfl_xor(part1, 32);
    if (lane < 32) {
        atomicAdd(out + n0 + nbl + l31, part0);
        atomicAdd(out + n0 + nbl + 32 + l31, part1);
    }
}

extern "C" void kernel_launch(void* const* d_in, const int* in_sizes, int n_in,
                              void* d_out, int out_size, void* d_ws, size_t ws_size,
                              hipStream_t stream) {
    const float* F = (const float*)d_in[0];   // features (N, K)
    const float* W = (const float*)d_in[1];   // w        (D, N)
    const float* E = (const float*)d_in[2];   // E        (K, D)
    const float* B = (const float*)d_in[3];   // b        (D,)
    float* out = (float*)d_out;               // (N,) f32

    unsigned short* ETf = (unsigned short*)d_ws;                      // 4 MB, fragment-major
    unsigned short* FBf = (unsigned short*)((char*)d_ws + (size_t)D_DIM * K_DIM * 2);  // 8 MB

    (void)hipMemsetAsync(d_out, 0, (size_t)out_size * sizeof(float), stream);
    transpose_E<<<dim3(D_DIM / 64, K_DIM / 64), 256, 0, stream>>>(E, ETf);
    convert_F<<<dim3(N_DIM / 32), 256, 0, stream>>>(F, FBf);
    gemm_fused<<<dim3(N_DIM / 128, D_DIM / 128), 256, 0, stream>>>(FBf, W, ETf, B, out);
}